// Round 9
// baseline (90.684 us; speedup 1.0000x reference)
//
#include <hip/hip_runtime.h>
#include <hip/hip_bf16.h>

#define N_NODES   50000
#define N_EDGES   625000
#define HF        128
#define MTILE     64
#define NTILES    ((N_EDGES + MTILE - 1) / MTILE)
#define NROWTILES (N_NODES / 16)                             // 3125 exact
#define W1F_BYTES ((size_t)4096 * 16)                        // 65,536
#define UV_BYTES  ((size_t)N_NODES * 256 * sizeof(short))    // 25,600,000
#define ES_BYTES  ((size_t)N_EDGES * 16)                     // 10,000,000
#define H_BYTES   (512 * 4)
#define WS_SORT   (W1F_BYTES + UV_BYTES + ES_BYTES + 2 * H_BYTES)  // ~35.67 MB
#define WS_PLAIN  (W1F_BYTES + UV_BYTES)
#define SC_CHUNK  1024

typedef __attribute__((ext_vector_type(8))) short s16x8;
typedef __attribute__((ext_vector_type(4))) float f32x4;

__device__ __forceinline__ short f2bf(float x) {
    unsigned u = __builtin_bit_cast(unsigned, x);
    u += 0x7FFFu + ((u >> 16) & 1u);          // round-to-nearest-even
    return (short)(u >> 16);
}
__device__ __forceinline__ float bf2f(short s) {
    return __builtin_bit_cast(float, ((unsigned)(unsigned short)s) << 16);
}

// ---------------------------------------------------------------------------
// conv_w (+hist zero): W -> fragment-ordered bf16; blocks 16..19 zero hist.
// ---------------------------------------------------------------------------
__global__ void conv_w_kernel(const float* __restrict__ W1, short* __restrict__ w1f,
                              int* __restrict__ hist) {
    int j = blockIdx.x * 256 + threadIdx.x;
    if (j < 4096) {
        const int lr  = j & 15;
        const int lg  = (j >> 4) & 3;
        const int ntg = (j >> 6) & 15;
        const int kt  = j >> 10;
        const int n2  = ntg * 16 + lr;
        const int kb  = kt * 32 + lg * 8;
        const float* wp = (n2 < 128) ? (W1 + (size_t)kb * 128 + n2)
                                     : (W1 + (size_t)(kb + 128) * 128 + (n2 - 128));
        s16x8 f;
        #pragma unroll
        for (int i = 0; i < 8; ++i) f[i] = f2bf(wp[(size_t)i * 128]);
        ((s16x8*)w1f)[j] = f;
    } else if (hist && j - 4096 < 512) {
        hist[j - 4096] = 0;
    }
}

// ---------------------------------------------------------------------------
// Sort pipeline: bucket = src >> 7 (391 buckets of 128 nodes).
// ---------------------------------------------------------------------------
__global__ __launch_bounds__(256) void hist_kernel(const int* __restrict__ src,
                                                   int* __restrict__ hist) {
    __shared__ int lh[512];
    const int t = threadIdx.x;
    lh[t] = 0; lh[t + 256] = 0;
    __syncthreads();
    for (int e = blockIdx.x * 256 + t; e < N_EDGES; e += gridDim.x * 256)
        atomicAdd(&lh[src[e] >> 7], 1);
    __syncthreads();
    if (lh[t])       atomicAdd(&hist[t],       lh[t]);
    if (lh[t + 256]) atomicAdd(&hist[t + 256], lh[t + 256]);
}

__global__ void scan_kernel(const int* __restrict__ hist, int* __restrict__ cursor) {
    __shared__ int sc[512];
    const int t = threadIdx.x;          // 512 threads
    const int v = hist[t];
    sc[t] = v;
    __syncthreads();
    for (int s = 1; s < 512; s <<= 1) {
        int x = (t >= s) ? sc[t - s] : 0;
        __syncthreads();
        sc[t] += x;
        __syncthreads();
    }
    cursor[t] = sc[t] - v;              // exclusive prefix
}

__global__ __launch_bounds__(256) void scatter_kernel(const int* __restrict__ src,
                                                      const int* __restrict__ dst,
                                                      int* __restrict__ cursor,
                                                      int4* __restrict__ esort) {
    __shared__ int h1[512], bbase[512], h2[512];
    const int t = threadIdx.x;
    const int base = blockIdx.x * SC_CHUNK;
    h1[t] = 0; h1[t + 256] = 0; h2[t] = 0; h2[t + 256] = 0;
    __syncthreads();

    int s_[4], d_[4], e_[4], b_[4];
    #pragma unroll
    for (int i = 0; i < 4; ++i) {
        const int e = base + i * 256 + t;
        e_[i] = e;
        if (e < N_EDGES) {
            s_[i] = src[e]; d_[i] = dst[e]; b_[i] = s_[i] >> 7;
            atomicAdd(&h1[b_[i]], 1);
        } else b_[i] = -1;
    }
    __syncthreads();
    {
        int c = h1[t];       if (c) bbase[t]       = atomicAdd(&cursor[t],       c);
        c = h1[t + 256];     if (c) bbase[t + 256] = atomicAdd(&cursor[t + 256], c);
    }
    __syncthreads();
    #pragma unroll
    for (int i = 0; i < 4; ++i) {
        if (b_[i] >= 0) {
            const int r = atomicAdd(&h2[b_[i]], 1);
            int4 rec; rec.x = s_[i]; rec.y = d_[i]; rec.z = e_[i]; rec.w = 0;
            esort[bbase[b_[i]] + r] = rec;
        }
    }
}

// ---------------------------------------------------------------------------
// UV GEMM v6: weights-stationary persistent + cross-tile register prefetch
// of the next h-chunk (v5 lock-stepped at 2 barriers/tile with no load in
// flight during compute; prefetch hides the per-tile HBM latency).
// ---------------------------------------------------------------------------
__global__ __launch_bounds__(256, 3) void uv_gemm6_kernel(
    const float* __restrict__ h,
    const short* __restrict__ w1f,
    const float* __restrict__ b1,
    short* __restrict__ UV)
{
    __shared__ short ldsA[16 * 128];     // 4 KB bf16 A tile (swizzled)
    __shared__ char  ldsC[4][2048];      // per-wave C slices (swizzled)

    const int t  = threadIdx.x;
    const int w  = t >> 6;
    const int l  = t & 63;
    const int lg = l >> 4;
    const int lr = l & 15;
    const int srow = t >> 4;
    const int sch  = t & 15;

    s16x8 bfrag[4][4];
    #pragma unroll
    for (int kt = 0; kt < 4; ++kt)
        #pragma unroll
        for (int nt = 0; nt < 4; ++nt)
            bfrag[kt][nt] = ((const s16x8*)w1f)[(kt * 16 + w * 4 + nt) * 64 + l];

    float b1v[4];
    #pragma unroll
    for (int nt = 0; nt < 4; ++nt)
        b1v[nt] = 0.5f * b1[(w * 64 + nt * 16 + lr) & 127];

    int tile = blockIdx.x;
    f32x4 pa, pb;
    {   // preload first tile's h chunk
        int gr = tile * 16 + srow; if (gr > N_NODES - 1) gr = N_NODES - 1;
        const float* hp = h + (size_t)gr * HF + sch * 8;
        pa = *reinterpret_cast<const f32x4*>(hp);
        pb = *reinterpret_cast<const f32x4*>(hp + 4);
    }

    while (tile < NROWTILES) {
        const int R0 = tile * 16;
        // convert staged regs -> swizzled LDS
        {
            s16x8 p;
            p[0]=f2bf(pa[0]); p[1]=f2bf(pa[1]); p[2]=f2bf(pa[2]); p[3]=f2bf(pa[3]);
            p[4]=f2bf(pb[0]); p[5]=f2bf(pb[1]); p[6]=f2bf(pb[2]); p[7]=f2bf(pb[3]);
            *reinterpret_cast<s16x8*>((char*)ldsA + srow * 256 + ((sch * 16) ^ ((srow & 7) << 4))) = p;
        }
        // prefetch next tile's h chunk (in flight across compute)
        const int next = tile + gridDim.x;
        if (next < NROWTILES) {
            int gr = next * 16 + srow; if (gr > N_NODES - 1) gr = N_NODES - 1;
            const float* hp = h + (size_t)gr * HF + sch * 8;
            pa = *reinterpret_cast<const f32x4*>(hp);
            pb = *reinterpret_cast<const f32x4*>(hp + 4);
        }
        __syncthreads();

        s16x8 afr[4];
        #pragma unroll
        for (int kt = 0; kt < 4; ++kt)
            afr[kt] = *reinterpret_cast<const s16x8*>(
                (char*)ldsA + lr * 256 + ((kt * 64 + lg * 16) ^ ((lr & 7) << 4)));

        f32x4 acc[4];
        #pragma unroll
        for (int nt = 0; nt < 4; ++nt) acc[nt] = (f32x4){0.f, 0.f, 0.f, 0.f};
        #pragma unroll
        for (int kt = 0; kt < 4; ++kt)
            #pragma unroll
            for (int nt = 0; nt < 4; ++nt)
                acc[nt] = __builtin_amdgcn_mfma_f32_16x16x32_bf16(afr[kt], bfrag[kt][nt], acc[nt], 0, 0, 0);

        char* Cb = ldsC[w];
        #pragma unroll
        for (int nt = 0; nt < 4; ++nt) {
            const int colb = nt * 32 + lr * 2;
            #pragma unroll
            for (int rr = 0; rr < 4; ++rr) {
                const int row = lg * 4 + rr;
                *(short*)(Cb + row * 128 + (colb ^ ((row & 7) << 4))) = f2bf(acc[nt][rr] + b1v[nt]);
            }
        }
        asm volatile("s_waitcnt lgkmcnt(0)" ::: "memory");

        #pragma unroll
        for (int i = 0; i < 2; ++i) {
            const int idx = l + i * 64;
            const int r2  = idx >> 3;
            const int ch  = idx & 7;
            s16x8 vv = *reinterpret_cast<const s16x8*>(Cb + r2 * 128 + ((ch * 16) ^ ((r2 & 7) << 4)));
            const int grow = R0 + r2;
            if (grow < N_NODES)
                *reinterpret_cast<s16x8*>(&UV[(size_t)grow * 256 + w * 64 + ch * 8]) = vv;
        }
        __syncthreads();
        tile = next;
    }
}

// ---------------------------------------------------------------------------
// Edge combine v4 (sorted records): out[rec.idx] = score(rec.src, rec.dst).
// Sorted-by-src stream makes each node's ~12.5 U-reads temporally adjacent
// -> U-side L2 misses collapse to compulsory (~13 MB).
// ---------------------------------------------------------------------------
__device__ __forceinline__ float dotrelu8(s16x8 u, s16x8 v, const float* w2v, int off) {
    float a = 0.f;
    #pragma unroll
    for (int j = 0; j < 8; ++j) {
        float s = bf2f(u[j]) + bf2f(v[j]);
        s = s > 0.f ? s : 0.f;
        a += s * w2v[off + j];
    }
    return a;
}

__global__ __launch_bounds__(256, 4) void edge_combine4_kernel(
    const short* __restrict__ UV,
    const int4*  __restrict__ esort,
    const float* __restrict__ W2,
    const float* __restrict__ b2,
    float* __restrict__ out)
{
    const int t  = threadIdx.x;
    const int w  = t >> 6;
    const int l  = t & 63;
    const int eg = l >> 3;
    const int dg = l & 7;
    const int dl = dg * 16;

    float w2v[16];
    #pragma unroll
    for (int j = 0; j < 16; ++j) w2v[j] = W2[dl + j];
    const float b2v = b2[0];

    const int gw = blockIdx.x * 4 + w;
    const int stride = gridDim.x * 4 * 32;

    for (int base = gw * 32; base < N_EDGES; base += stride) {
        int j = base + (l & 31); if (j > N_EDGES - 1) j = N_EDGES - 1;
        const int4 rec = esort[j];

        int s0 = __shfl(rec.x, 0 * 8 + eg, 64), d0 = __shfl(rec.y, 0 * 8 + eg, 64);
        int s1 = __shfl(rec.x, 1 * 8 + eg, 64), d1 = __shfl(rec.y, 1 * 8 + eg, 64);
        int s2 = __shfl(rec.x, 2 * 8 + eg, 64), d2 = __shfl(rec.y, 2 * 8 + eg, 64);
        int s3 = __shfl(rec.x, 3 * 8 + eg, 64), d3 = __shfl(rec.y, 3 * 8 + eg, 64);

        const s16x8* up0 = (const s16x8*)(UV + (size_t)s0 * 256 + dl);
        const s16x8* vp0 = (const s16x8*)(UV + (size_t)d0 * 256 + 128 + dl);
        const s16x8* up1 = (const s16x8*)(UV + (size_t)s1 * 256 + dl);
        const s16x8* vp1 = (const s16x8*)(UV + (size_t)d1 * 256 + 128 + dl);
        const s16x8* up2 = (const s16x8*)(UV + (size_t)s2 * 256 + dl);
        const s16x8* vp2 = (const s16x8*)(UV + (size_t)d2 * 256 + 128 + dl);
        const s16x8* up3 = (const s16x8*)(UV + (size_t)s3 * 256 + dl);
        const s16x8* vp3 = (const s16x8*)(UV + (size_t)d3 * 256 + 128 + dl);
        s16x8 ua0 = up0[0], ub0 = up0[1], va0 = vp0[0], vb0 = vp0[1];
        s16x8 ua1 = up1[0], ub1 = up1[1], va1 = vp1[0], vb1 = vp1[1];
        s16x8 ua2 = up2[0], ub2 = up2[1], va2 = vp2[0], vb2 = vp2[1];
        s16x8 ua3 = up3[0], ub3 = up3[1], va3 = vp3[0], vb3 = vp3[1];
        __builtin_amdgcn_sched_barrier(0);

        float a0 = dotrelu8(ua0, va0, w2v, 0) + dotrelu8(ub0, vb0, w2v, 8);
        float a1 = dotrelu8(ua1, va1, w2v, 0) + dotrelu8(ub1, vb1, w2v, 8);
        float a2 = dotrelu8(ua2, va2, w2v, 0) + dotrelu8(ub2, vb2, w2v, 8);
        float a3 = dotrelu8(ua3, va3, w2v, 0) + dotrelu8(ub3, vb3, w2v, 8);

        #pragma unroll
        for (int m = 1; m <= 4; m <<= 1) {
            a0 += __shfl_xor(a0, m, 64);
            a1 += __shfl_xor(a1, m, 64);
            a2 += __shfl_xor(a2, m, 64);
            a3 += __shfl_xor(a3, m, 64);
        }

        const int i0 = __shfl(rec.z, 0 * 8 + eg, 64);
        const int i1 = __shfl(rec.z, 1 * 8 + eg, 64);
        const int i2 = __shfl(rec.z, 2 * 8 + eg, 64);
        const int i3 = __shfl(rec.z, 3 * 8 + eg, 64);
        if (dg == 0) {
            if (base + 0 * 8 + eg < N_EDGES) out[i0] = a0 + b2v;
            if (base + 1 * 8 + eg < N_EDGES) out[i1] = a1 + b2v;
            if (base + 2 * 8 + eg < N_EDGES) out[i2] = a2 + b2v;
            if (base + 3 * 8 + eg < N_EDGES) out[i3] = a3 + b2v;
        }
    }
}

// ---------------------------------------------------------------------------
// Unsorted fallback edge kernel (round-8 behavior)
// ---------------------------------------------------------------------------
__global__ __launch_bounds__(256, 4) void edge_combine3_kernel(
    const short* __restrict__ UV,
    const int*   __restrict__ src,
    const int*   __restrict__ dst,
    const float* __restrict__ W2,
    const float* __restrict__ b2,
    float* __restrict__ out)
{
    const int t  = threadIdx.x;
    const int w  = t >> 6;
    const int l  = t & 63;
    const int eg = l >> 3;
    const int dg = l & 7;
    const int dl = dg * 16;

    float w2v[16];
    #pragma unroll
    for (int j = 0; j < 16; ++j) w2v[j] = W2[dl + j];
    const float b2v = b2[0];

    const int gw = blockIdx.x * 4 + w;
    const int stride = gridDim.x * 4 * 32;

    int base = gw * 32;
    int jj0 = base + (l & 31); if (jj0 > N_EDGES - 1) jj0 = N_EDGES - 1;
    int ids = (l < 32) ? src[jj0] : dst[jj0];

    for (; base < N_EDGES; base += stride) {
        int s0 = __shfl(ids, 0 * 8 + eg, 64), d0 = __shfl(ids, 32 + 0 * 8 + eg, 64);
        int s1 = __shfl(ids, 1 * 8 + eg, 64), d1 = __shfl(ids, 32 + 1 * 8 + eg, 64);
        int s2 = __shfl(ids, 2 * 8 + eg, 64), d2 = __shfl(ids, 32 + 2 * 8 + eg, 64);
        int s3 = __shfl(ids, 3 * 8 + eg, 64), d3 = __shfl(ids, 32 + 3 * 8 + eg, 64);

        const s16x8* up0 = (const s16x8*)(UV + (size_t)s0 * 256 + dl);
        const s16x8* vp0 = (const s16x8*)(UV + (size_t)d0 * 256 + 128 + dl);
        const s16x8* up1 = (const s16x8*)(UV + (size_t)s1 * 256 + dl);
        const s16x8* vp1 = (const s16x8*)(UV + (size_t)d1 * 256 + 128 + dl);
        const s16x8* up2 = (const s16x8*)(UV + (size_t)s2 * 256 + dl);
        const s16x8* vp2 = (const s16x8*)(UV + (size_t)d2 * 256 + 128 + dl);
        const s16x8* up3 = (const s16x8*)(UV + (size_t)s3 * 256 + dl);
        const s16x8* vp3 = (const s16x8*)(UV + (size_t)d3 * 256 + 128 + dl);
        s16x8 ua0 = up0[0], ub0 = up0[1], va0 = vp0[0], vb0 = vp0[1];
        s16x8 ua1 = up1[0], ub1 = up1[1], va1 = vp1[0], vb1 = vp1[1];
        s16x8 ua2 = up2[0], ub2 = up2[1], va2 = vp2[0], vb2 = vp2[1];
        s16x8 ua3 = up3[0], ub3 = up3[1], va3 = vp3[0], vb3 = vp3[1];

        const int nb = base + stride;
        if (nb < N_EDGES) {
            int j2 = nb + (l & 31); if (j2 > N_EDGES - 1) j2 = N_EDGES - 1;
            ids = (l < 32) ? src[j2] : dst[j2];
        }
        __builtin_amdgcn_sched_barrier(0);

        float a0 = dotrelu8(ua0, va0, w2v, 0) + dotrelu8(ub0, vb0, w2v, 8);
        float a1 = dotrelu8(ua1, va1, w2v, 0) + dotrelu8(ub1, vb1, w2v, 8);
        float a2 = dotrelu8(ua2, va2, w2v, 0) + dotrelu8(ub2, vb2, w2v, 8);
        float a3 = dotrelu8(ua3, va3, w2v, 0) + dotrelu8(ub3, vb3, w2v, 8);

        #pragma unroll
        for (int m = 1; m <= 4; m <<= 1) {
            a0 += __shfl_xor(a0, m, 64);
            a1 += __shfl_xor(a1, m, 64);
            a2 += __shfl_xor(a2, m, 64);
            a3 += __shfl_xor(a3, m, 64);
        }

        if (dg == 0) {
            if (base + 0 * 8 + eg < N_EDGES) __builtin_nontemporal_store(a0 + b2v, &out[base + 0 * 8 + eg]);
            if (base + 1 * 8 + eg < N_EDGES) __builtin_nontemporal_store(a1 + b2v, &out[base + 1 * 8 + eg]);
            if (base + 2 * 8 + eg < N_EDGES) __builtin_nontemporal_store(a2 + b2v, &out[base + 2 * 8 + eg]);
            if (base + 3 * 8 + eg < N_EDGES) __builtin_nontemporal_store(a3 + b2v, &out[base + 3 * 8 + eg]);
        }
    }
}

extern "C" void kernel_launch(void* const* d_in, const int* in_sizes, int n_in,
                              void* d_out, int out_size, void* d_ws, size_t ws_size,
                              hipStream_t stream) {
    const float* h   = (const float*)d_in[0];
    const int*   src = (const int*)  d_in[1];
    const int*   dst = (const int*)  d_in[2];
    const float* W1  = (const float*)d_in[3];
    const float* b1  = (const float*)d_in[4];
    const float* W2  = (const float*)d_in[5];
    const float* b2  = (const float*)d_in[6];
    float* out = (float*)d_out;

    char* ws = (char*)d_ws;
    short* w1f = (short*)ws;
    short* UV  = (short*)(ws + W1F_BYTES);

    if (ws_size >= WS_SORT) {
        int4* esort = (int4*)(ws + W1F_BYTES + UV_BYTES);
        int*  hist  = (int*)(ws + W1F_BYTES + UV_BYTES + ES_BYTES);
        int*  curs  = hist + 512;

        conv_w_kernel<<<20, 256, 0, stream>>>(W1, w1f, hist);
        uv_gemm6_kernel<<<1024, 256, 0, stream>>>(h, w1f, b1, UV);
        hist_kernel<<<256, 256, 0, stream>>>(src, hist);
        scan_kernel<<<1, 512, 0, stream>>>(hist, curs);
        scatter_kernel<<<(N_EDGES + SC_CHUNK - 1) / SC_CHUNK, 256, 0, stream>>>(src, dst, curs, esort);
        edge_combine4_kernel<<<1024, 256, 0, stream>>>(UV, esort, W2, b2, out);
    } else {
        conv_w_kernel<<<16, 256, 0, stream>>>(W1, w1f, nullptr);
        uv_gemm6_kernel<<<1024, 256, 0, stream>>>(h, w1f, b1, UV);
        edge_combine3_kernel<<<1024, 256, 0, stream>>>(UV, src, dst, W2, b2, out);
    }
}

// Round 10
// 65.930 us; speedup vs baseline: 1.3755x; 1.3755x over previous
//
#include <hip/hip_runtime.h>
#include <hip/hip_bf16.h>

#define N_NODES   50000
#define N_EDGES   625000
#define HF        128
#define MTILE     64
#define NTILES    ((N_EDGES + MTILE - 1) / MTILE)
#define NROWTILES (N_NODES / 16)                             // 3125 exact
#define HB_BYTES  ((size_t)N_NODES * HF * sizeof(short))     // v2 fallback
#define W1F_BYTES ((size_t)4096 * 16)                        // 65,536
#define UV_BYTES  ((size_t)N_NODES * 256 * sizeof(short))    // 25,600,000
#define WS_NEED   (W1F_BYTES + UV_BYTES)

typedef __attribute__((ext_vector_type(8))) short s16x8;
typedef __attribute__((ext_vector_type(4))) float f32x4;

__device__ __forceinline__ short f2bf(float x) {
    unsigned u = __builtin_bit_cast(unsigned, x);
    u += 0x7FFFu + ((u >> 16) & 1u);          // round-to-nearest-even
    return (short)(u >> 16);
}
__device__ __forceinline__ float bf2f(short s) {
    return __builtin_bit_cast(float, ((unsigned)(unsigned short)s) << 16);
}

// ---------------------------------------------------------------------------
// W -> fragment-ordered bf16. Combined B = [W1[0:128,:] | W1[128:256,:]],
// K=128, N=256 (U cols 0..127 top half of W1, V cols 128..255 bottom half).
// ---------------------------------------------------------------------------
__global__ void conv_w_kernel(const float* __restrict__ W1, short* __restrict__ w1f) {
    int j = blockIdx.x * 256 + threadIdx.x;
    if (j < 4096) {
        const int lr  = j & 15;
        const int lg  = (j >> 4) & 3;
        const int ntg = (j >> 6) & 15;
        const int kt  = j >> 10;
        const int n2  = ntg * 16 + lr;
        const int kb  = kt * 32 + lg * 8;
        const float* wp = (n2 < 128) ? (W1 + (size_t)kb * 128 + n2)
                                     : (W1 + (size_t)(kb + 128) * 128 + (n2 - 128));
        s16x8 f;
        #pragma unroll
        for (int i = 0; i < 8; ++i) f[i] = f2bf(wp[(size_t)i * 128]);
        ((s16x8*)w1f)[j] = f;
    }
}

// ---------------------------------------------------------------------------
// UV GEMM v6 (round-9 version, kept): weights-stationary persistent +
// cross-tile register prefetch of the next h chunk.
// ---------------------------------------------------------------------------
__global__ __launch_bounds__(256, 3) void uv_gemm6_kernel(
    const float* __restrict__ h,
    const short* __restrict__ w1f,
    const float* __restrict__ b1,
    short* __restrict__ UV)
{
    __shared__ short ldsA[16 * 128];     // 4 KB bf16 A tile (swizzled)
    __shared__ char  ldsC[4][2048];      // per-wave C slices (swizzled)

    const int t  = threadIdx.x;
    const int w  = t >> 6;
    const int l  = t & 63;
    const int lg = l >> 4;
    const int lr = l & 15;
    const int srow = t >> 4;
    const int sch  = t & 15;

    s16x8 bfrag[4][4];
    #pragma unroll
    for (int kt = 0; kt < 4; ++kt)
        #pragma unroll
        for (int nt = 0; nt < 4; ++nt)
            bfrag[kt][nt] = ((const s16x8*)w1f)[(kt * 16 + w * 4 + nt) * 64 + l];

    float b1v[4];
    #pragma unroll
    for (int nt = 0; nt < 4; ++nt)
        b1v[nt] = 0.5f * b1[(w * 64 + nt * 16 + lr) & 127];

    int tile = blockIdx.x;
    f32x4 pa, pb;
    {
        int gr = tile * 16 + srow; if (gr > N_NODES - 1) gr = N_NODES - 1;
        const float* hp = h + (size_t)gr * HF + sch * 8;
        pa = *reinterpret_cast<const f32x4*>(hp);
        pb = *reinterpret_cast<const f32x4*>(hp + 4);
    }

    while (tile < NROWTILES) {
        const int R0 = tile * 16;
        {
            s16x8 p;
            p[0]=f2bf(pa[0]); p[1]=f2bf(pa[1]); p[2]=f2bf(pa[2]); p[3]=f2bf(pa[3]);
            p[4]=f2bf(pb[0]); p[5]=f2bf(pb[1]); p[6]=f2bf(pb[2]); p[7]=f2bf(pb[3]);
            *reinterpret_cast<s16x8*>((char*)ldsA + srow * 256 + ((sch * 16) ^ ((srow & 7) << 4))) = p;
        }
        const int next = tile + gridDim.x;
        if (next < NROWTILES) {
            int gr = next * 16 + srow; if (gr > N_NODES - 1) gr = N_NODES - 1;
            const float* hp = h + (size_t)gr * HF + sch * 8;
            pa = *reinterpret_cast<const f32x4*>(hp);
            pb = *reinterpret_cast<const f32x4*>(hp + 4);
        }
        __syncthreads();

        s16x8 afr[4];
        #pragma unroll
        for (int kt = 0; kt < 4; ++kt)
            afr[kt] = *reinterpret_cast<const s16x8*>(
                (char*)ldsA + lr * 256 + ((kt * 64 + lg * 16) ^ ((lr & 7) << 4)));

        f32x4 acc[4];
        #pragma unroll
        for (int nt = 0; nt < 4; ++nt) acc[nt] = (f32x4){0.f, 0.f, 0.f, 0.f};
        #pragma unroll
        for (int kt = 0; kt < 4; ++kt)
            #pragma unroll
            for (int nt = 0; nt < 4; ++nt)
                acc[nt] = __builtin_amdgcn_mfma_f32_16x16x32_bf16(afr[kt], bfrag[kt][nt], acc[nt], 0, 0, 0);

        char* Cb = ldsC[w];
        #pragma unroll
        for (int nt = 0; nt < 4; ++nt) {
            const int colb = nt * 32 + lr * 2;
            #pragma unroll
            for (int rr = 0; rr < 4; ++rr) {
                const int row = lg * 4 + rr;
                *(short*)(Cb + row * 128 + (colb ^ ((row & 7) << 4))) = f2bf(acc[nt][rr] + b1v[nt]);
            }
        }
        asm volatile("s_waitcnt lgkmcnt(0)" ::: "memory");

        #pragma unroll
        for (int i = 0; i < 2; ++i) {
            const int idx = l + i * 64;
            const int r2  = idx >> 3;
            const int ch  = idx & 7;
            s16x8 vv = *reinterpret_cast<const s16x8*>(Cb + r2 * 128 + ((ch * 16) ^ ((r2 & 7) << 4)));
            const int grow = R0 + r2;
            if (grow < N_NODES)
                *reinterpret_cast<s16x8*>(&UV[(size_t)grow * 256 + w * 64 + ch * 8]) = vv;
        }
        __syncthreads();
        tile = next;
    }
}

// ---------------------------------------------------------------------------
// Edge combine v5: SEGMENT-CONTIGUOUS gathers. 16 lanes per edge; lane c
// loads the c-th contiguous 16B chunk of the 256B U row (resp. V row), so
// each team's load is one 256B span = 4x64B transactions (compulsory
// minimum; 8 tx/edge total). Rounds 4-9's 8-lane dim-sliced layout had
// 32B-stride addresses that defeated segment coalescing -> TA-issue bound
// at ~0.78 lane-addr/cyc/CU = the invariant 42us.
// ---------------------------------------------------------------------------
__global__ __launch_bounds__(256, 4) void edge_combine5_kernel(
    const short* __restrict__ UV,
    const int*   __restrict__ src,
    const int*   __restrict__ dst,
    const float* __restrict__ W2,
    const float* __restrict__ b2,
    float* __restrict__ out)
{
    const int t  = threadIdx.x;
    const int w  = t >> 6;
    const int l  = t & 63;
    const int tm = l >> 4;         // team 0..3 (edge within quad)
    const int c  = l & 15;         // contiguous 16B chunk 0..15 (dims c*8..+7)

    float w2v[8];
    #pragma unroll
    for (int j = 0; j < 8; ++j) w2v[j] = W2[c * 8 + j];
    const float b2v = b2[0];

    const int gw = blockIdx.x * 4 + w;
    const int nw = gridDim.x * 4;

    for (int eb = gw * 64; eb < N_EDGES; eb += nw * 64) {
        // one coalesced id-load pair covers 64 edges = 16 quads
        int ee = eb + l; if (ee > N_EDGES - 1) ee = N_EDGES - 1;
        const int ids_s = src[ee];
        const int ids_d = dst[ee];

        #pragma unroll 4
        for (int k = 0; k < 16; ++k) {
            const int e = eb + k * 4 + tm;
            const int s = __shfl(ids_s, k * 4 + tm, 64);
            const int d = __shfl(ids_d, k * 4 + tm, 64);

            // U: 256B span [s*512 .. +256); V: [d*512+256 .. +512)
            s16x8 u = *reinterpret_cast<const s16x8*>(UV + (size_t)s * 256 + c * 8);
            s16x8 v = *reinterpret_cast<const s16x8*>(UV + (size_t)d * 256 + 128 + c * 8);

            float a = 0.f;
            #pragma unroll
            for (int j = 0; j < 8; ++j) {
                float x = bf2f(u[j]) + bf2f(v[j]);
                x = x > 0.f ? x : 0.f;
                a += x * w2v[j];
            }
            #pragma unroll
            for (int m = 1; m <= 8; m <<= 1)
                a += __shfl_xor(a, m, 64);

            if (c == 0 && e < N_EDGES)
                __builtin_nontemporal_store(a + b2v, &out[e]);
        }
    }
}

// ---------------------------------------------------------------------------
// v2 fallback (only if ws too small): bf16 h + direct-gather MFMA
// ---------------------------------------------------------------------------
__global__ void conv_h_kernel(const float* __restrict__ h, short* __restrict__ hb) {
    int i = blockIdx.x * blockDim.x + threadIdx.x;
    const int n8 = N_NODES * HF / 8;
    if (i < n8) {
        f32x4 a = ((const f32x4*)h)[i * 2];
        f32x4 b = ((const f32x4*)h)[i * 2 + 1];
        s16x8 p;
        p[0]=f2bf(a[0]); p[1]=f2bf(a[1]); p[2]=f2bf(a[2]); p[3]=f2bf(a[3]);
        p[4]=f2bf(b[0]); p[5]=f2bf(b[1]); p[6]=f2bf(b[2]); p[7]=f2bf(b[3]);
        ((s16x8*)hb)[i] = p;
    }
}

__device__ __forceinline__ void gatherA(const short* __restrict__ hb,
                                        int sid, int did, int lg, s16x8 (&A)[8]) {
    const s16x8* bs = (const s16x8*)(hb + (size_t)sid * HF);
    const s16x8* bd = (const s16x8*)(hb + (size_t)did * HF);
    A[0] = bs[lg];      A[1] = bs[4 + lg];  A[2] = bs[8 + lg];  A[3] = bs[12 + lg];
    A[4] = bd[lg];      A[5] = bd[4 + lg];  A[6] = bd[8 + lg];  A[7] = bd[12 + lg];
}

__device__ __forceinline__ void step_tile_v2(
    int tile, int g,
    const short* __restrict__ hb,
    const int* __restrict__ src, const int* __restrict__ dst,
    s16x8 (&Acur)[8], s16x8 (&Anext)[8],
    int sidg, int didg, int& sid2, int& did2,
    const s16x8 (&bfrag)[8][4],
    const float (&b1v)[4], const float (&w2v)[4], float b2v,
    float* __restrict__ out,
    float (&lds_p)[2][2][MTILE], int pp,
    int t, int r, int c, int lg, int lr, int myrow)
{
    gatherA(hb, sidg, didg, lg, Anext);
    {
        int e = (tile + 2 * g) * MTILE + myrow;
        e = e < N_EDGES ? e : N_EDGES - 1;
        sid2 = src[e]; did2 = dst[e];
    }
    f32x4 acc[4];
    #pragma unroll
    for (int nt = 0; nt < 4; ++nt) acc[nt] = (f32x4){0.f, 0.f, 0.f, 0.f};
    #pragma unroll
    for (int kt = 0; kt < 8; ++kt)
        #pragma unroll
        for (int nt = 0; nt < 4; ++nt)
            acc[nt] = __builtin_amdgcn_mfma_f32_16x16x32_bf16(Acur[kt], bfrag[kt][nt], acc[nt], 0, 0, 0);

    float s0[4];
    #pragma unroll
    for (int rr = 0; rr < 4; ++rr) {
        float a = 0.f;
        #pragma unroll
        for (int nt = 0; nt < 4; ++nt) {
            float v = acc[nt][rr] + b1v[nt];
            v = v > 0.f ? v : 0.f;
            a += v * w2v[nt];
        }
        s0[rr] = a;
    }
    #pragma unroll
    for (int mask = 1; mask <= 8; mask <<= 1)
        #pragma unroll
        for (int rr = 0; rr < 4; ++rr)
            s0[rr] += __shfl_xor(s0[rr], mask, 64);

    if (lr == 0) {
        #pragma unroll
        for (int rr = 0; rr < 4; ++rr)
            lds_p[pp][c][r * 16 + lg * 4 + rr] = s0[rr];
    }
    asm volatile("s_waitcnt lgkmcnt(0)" ::: "memory");
    __builtin_amdgcn_s_barrier();
    asm volatile("" ::: "memory");

    if (t < MTILE) {
        int e = tile * MTILE + t;
        if (e < N_EDGES)
            out[e] = lds_p[pp][0][t] + lds_p[pp][1][t] + b2v;
    }
}

__global__ __launch_bounds__(512, 2) void mlp_edge_score_v2(
    const short* __restrict__ hb,
    const int*   __restrict__ src,
    const int*   __restrict__ dst,
    const float* __restrict__ W1,
    const float* __restrict__ b1,
    const float* __restrict__ W2,
    const float* __restrict__ b2,
    float* __restrict__ out)
{
    __shared__ float lds_p[2][2][MTILE];

    const int t  = threadIdx.x;
    const int w  = t >> 6;
    const int l  = t & 63;
    const int r  = w >> 1;
    const int c  = w & 1;
    const int lg = l >> 4;
    const int lr = l & 15;
    const int myrow = r * 16 + lr;

    s16x8 bfrag[8][4];
    #pragma unroll
    for (int kt = 0; kt < 8; ++kt)
        #pragma unroll
        for (int nt = 0; nt < 4; ++nt) {
            const int n  = c * 64 + nt * 16 + lr;
            const int kb = kt * 32 + lg * 8;
            s16x8 f;
            #pragma unroll
            for (int i = 0; i < 8; ++i) f[i] = f2bf(W1[(size_t)(kb + i) * HF + n]);
            bfrag[kt][nt] = f;
        }
    float b1v[4], w2v[4];
    #pragma unroll
    for (int nt = 0; nt < 4; ++nt) {
        const int n = c * 64 + nt * 16 + lr;
        b1v[nt] = b1[n];
        w2v[nt] = W2[n];
    }
    const float b2v = b2[0];

    const int g = gridDim.x;
    const int tile0 = blockIdx.x;

    s16x8 Aa[8], Ab[8];
    {
        int e = tile0 * MTILE + myrow;
        e = e < N_EDGES ? e : N_EDGES - 1;
        gatherA(hb, src[e], dst[e], lg, Aa);
    }
    int sidA, didA, sidB, didB;
    {
        int e = (tile0 + g) * MTILE + myrow;
        e = e < N_EDGES ? e : N_EDGES - 1;
        sidA = src[e]; didA = dst[e];
    }

    int pp = 0;
    for (int tile = tile0; tile < NTILES; tile += 2 * g) {
        step_tile_v2(tile, g, hb, src, dst, Aa, Ab, sidA, didA, sidB, didB,
                     bfrag, b1v, w2v, b2v, out, lds_p, pp, t, r, c, lg, lr, myrow);
        pp ^= 1;
        if (tile + g < NTILES) {
            step_tile_v2(tile + g, g, hb, src, dst, Ab, Aa, sidB, didB, sidA, didA,
                         bfrag, b1v, w2v, b2v, out, lds_p, pp, t, r, c, lg, lr, myrow);
            pp ^= 1;
        }
    }
}

extern "C" void kernel_launch(void* const* d_in, const int* in_sizes, int n_in,
                              void* d_out, int out_size, void* d_ws, size_t ws_size,
                              hipStream_t stream) {
    const float* h   = (const float*)d_in[0];
    const int*   src = (const int*)  d_in[1];
    const int*   dst = (const int*)  d_in[2];
    const float* W1  = (const float*)d_in[3];
    const float* b1  = (const float*)d_in[4];
    const float* W2  = (const float*)d_in[5];
    const float* b2  = (const float*)d_in[6];
    float* out = (float*)d_out;

    if (ws_size >= WS_NEED) {
        char* ws = (char*)d_ws;
        short* w1f = (short*)ws;
        short* UV  = (short*)(ws + W1F_BYTES);

        conv_w_kernel<<<16, 256, 0, stream>>>(W1, w1f);
        uv_gemm6_kernel<<<1024, 256, 0, stream>>>(h, w1f, b1, UV);
        edge_combine5_kernel<<<1024, 256, 0, stream>>>(UV, src, dst, W2, b2, out);
    } else {
        short* hb = (short*)d_ws;
        const int n8 = N_NODES * HF / 8;
        conv_h_kernel<<<(n8 + 255) / 256, 256, 0, stream>>>(h, hb);
        mlp_edge_score_v2<<<256, 512, 0, stream>>>(hb, src, dst, W1, b1, W2, b2, out);
    }
}

// Round 11
// 48.511 us; speedup vs baseline: 1.8694x; 1.3591x over previous
//
#include <hip/hip_runtime.h>
#include <hip/hip_bf16.h>

#define N_NODES   50000
#define N_EDGES   625000
#define HF        128
#define MTILE     64
#define NTILES    ((N_EDGES + MTILE - 1) / MTILE)
#define NROWTILES (N_NODES / 16)                             // 3125 exact
#define HB_BYTES  ((size_t)N_NODES * HF * sizeof(short))     // v2 fallback
#define W1F_BYTES ((size_t)4096 * 16)                        // 65,536
#define UVQ_BYTES ((size_t)N_NODES * 256)                    // 12,800,000
#define SCL_BYTES ((size_t)N_NODES * 8)                      // 400,000
#define WS_NEED   (W1F_BYTES + UVQ_BYTES + SCL_BYTES)        // ~13.27 MB

typedef __attribute__((ext_vector_type(8))) short s16x8;
typedef __attribute__((ext_vector_type(4))) float f32x4;
typedef __attribute__((ext_vector_type(4))) unsigned int u32x4;

__device__ __forceinline__ short f2bf(float x) {
    unsigned u = __builtin_bit_cast(unsigned, x);
    u += 0x7FFFu + ((u >> 16) & 1u);          // round-to-nearest-even
    return (short)(u >> 16);
}
__device__ __forceinline__ float bf2f(short s) {
    return __builtin_bit_cast(float, ((unsigned)(unsigned short)s) << 16);
}

// ---------------------------------------------------------------------------
// W -> fragment-ordered bf16. Combined B = [W1[0:128,:] | W1[128:256,:]],
// K=128, N=256 (U cols 0..127 top half of W1, V cols 128..255 bottom half).
// ---------------------------------------------------------------------------
__global__ void conv_w_kernel(const float* __restrict__ W1, short* __restrict__ w1f) {
    int j = blockIdx.x * 256 + threadIdx.x;
    if (j < 4096) {
        const int lr  = j & 15;
        const int lg  = (j >> 4) & 3;
        const int ntg = (j >> 6) & 15;
        const int kt  = j >> 10;
        const int n2  = ntg * 16 + lr;
        const int kb  = kt * 32 + lg * 8;
        const float* wp = (n2 < 128) ? (W1 + (size_t)kb * 128 + n2)
                                     : (W1 + (size_t)(kb + 128) * 128 + (n2 - 128));
        s16x8 f;
        #pragma unroll
        for (int i = 0; i < 8; ++i) f[i] = f2bf(wp[(size_t)i * 128]);
        ((s16x8*)w1f)[j] = f;
    }
}

// ---------------------------------------------------------------------------
// UV GEMM v7: v6 structure (weights-stationary persistent + h prefetch)
// with an int8 quantizing epilogue: per-row amax via shfl+LDS reduce,
// biased-uint8 quantize (q = round(val*127/rowmax)+128), scales to scl[].
// Halves the edge kernel's gather payload: 512B/edge -> 256B + 8B scales.
// ---------------------------------------------------------------------------
__global__ __launch_bounds__(256, 3) void uv_gemm7_kernel(
    const float* __restrict__ h,
    const short* __restrict__ w1f,
    const float* __restrict__ b1,
    unsigned char* __restrict__ UVq,
    float2* __restrict__ scl)
{
    __shared__ short ldsA[16 * 128];              // 4 KB bf16 A tile (swizzled)
    __shared__ float rm[4][16];                   // per-wave row maxes
    __shared__ __align__(16) char qt[16][272];    // int8 C tile (+16B pad)

    const int t  = threadIdx.x;
    const int w  = t >> 6;
    const int l  = t & 63;
    const int lg = l >> 4;
    const int lr = l & 15;
    const int srow = t >> 4;
    const int sch  = t & 15;
    const int side = w >> 1;                      // 0 = U (cols 0..127), 1 = V

    s16x8 bfrag[4][4];
    #pragma unroll
    for (int kt = 0; kt < 4; ++kt)
        #pragma unroll
        for (int nt = 0; nt < 4; ++nt)
            bfrag[kt][nt] = ((const s16x8*)w1f)[(kt * 16 + w * 4 + nt) * 64 + l];

    float b1v[4];
    #pragma unroll
    for (int nt = 0; nt < 4; ++nt)
        b1v[nt] = 0.5f * b1[(w * 64 + nt * 16 + lr) & 127];

    int tile = blockIdx.x;
    f32x4 pa, pb;
    {
        int gr = tile * 16 + srow; if (gr > N_NODES - 1) gr = N_NODES - 1;
        const float* hp = h + (size_t)gr * HF + sch * 8;
        pa = *reinterpret_cast<const f32x4*>(hp);
        pb = *reinterpret_cast<const f32x4*>(hp + 4);
    }

    while (tile < NROWTILES) {
        const int R0 = tile * 16;
        {
            s16x8 p;
            p[0]=f2bf(pa[0]); p[1]=f2bf(pa[1]); p[2]=f2bf(pa[2]); p[3]=f2bf(pa[3]);
            p[4]=f2bf(pb[0]); p[5]=f2bf(pb[1]); p[6]=f2bf(pb[2]); p[7]=f2bf(pb[3]);
            *reinterpret_cast<s16x8*>((char*)ldsA + srow * 256 + ((sch * 16) ^ ((srow & 7) << 4))) = p;
        }
        const int next = tile + gridDim.x;
        if (next < NROWTILES) {
            int gr = next * 16 + srow; if (gr > N_NODES - 1) gr = N_NODES - 1;
            const float* hp = h + (size_t)gr * HF + sch * 8;
            pa = *reinterpret_cast<const f32x4*>(hp);
            pb = *reinterpret_cast<const f32x4*>(hp + 4);
        }
        __syncthreads();

        s16x8 afr[4];
        #pragma unroll
        for (int kt = 0; kt < 4; ++kt)
            afr[kt] = *reinterpret_cast<const s16x8*>(
                (char*)ldsA + lr * 256 + ((kt * 64 + lg * 16) ^ ((lr & 7) << 4)));

        f32x4 acc[4];
        #pragma unroll
        for (int nt = 0; nt < 4; ++nt) acc[nt] = (f32x4){0.f, 0.f, 0.f, 0.f};
        #pragma unroll
        for (int kt = 0; kt < 4; ++kt)
            #pragma unroll
            for (int nt = 0; nt < 4; ++nt)
                acc[nt] = __builtin_amdgcn_mfma_f32_16x16x32_bf16(afr[kt], bfrag[kt][nt], acc[nt], 0, 0, 0);

        // ---- bias + per-row absmax (rows = lg*4+rr; reduce over 16 lr lanes) ----
        float val[4][4];                 // [nt][rr]
        float am[4];
        #pragma unroll
        for (int rr = 0; rr < 4; ++rr) am[rr] = 0.f;
        #pragma unroll
        for (int nt = 0; nt < 4; ++nt)
            #pragma unroll
            for (int rr = 0; rr < 4; ++rr) {
                float v = acc[nt][rr] + b1v[nt];
                val[nt][rr] = v;
                float a = fabsf(v);
                am[rr] = a > am[rr] ? a : am[rr];
            }
        #pragma unroll
        for (int m = 1; m <= 8; m <<= 1)
            #pragma unroll
            for (int rr = 0; rr < 4; ++rr) {
                float o = __shfl_xor(am[rr], m, 64);
                am[rr] = o > am[rr] ? o : am[rr];
            }
        if (lr == 0) {
            #pragma unroll
            for (int rr = 0; rr < 4; ++rr) rm[w][lg * 4 + rr] = am[rr];
        }
        __syncthreads();

        // ---- quantize to biased uint8, write qt ----
        #pragma unroll
        for (int rr = 0; rr < 4; ++rr) {
            const int row = lg * 4 + rr;
            const float rmax = fmaxf(rm[side * 2][row], rm[side * 2 + 1][row]);
            const float inv = rmax > 0.f ? 127.f / rmax : 0.f;
            #pragma unroll
            for (int nt = 0; nt < 4; ++nt) {
                int q = (int)rintf(val[nt][rr] * inv) + 128;
                q = q < 0 ? 0 : (q > 255 ? 255 : q);
                qt[row][w * 64 + nt * 16 + lr] = (char)q;
            }
        }
        if (t < 16) {
            const float sU = fmaxf(rm[0][t], rm[1][t]) * (1.f / 127.f);
            const float sV = fmaxf(rm[2][t], rm[3][t]) * (1.f / 127.f);
            const int grow = R0 + t;
            if (grow < N_NODES) {
                float2 s2; s2.x = sU; s2.y = sV;
                scl[grow] = s2;
            }
        }
        __syncthreads();

        // ---- coalesced 16B store of the int8 tile ----
        {
            const int row = t >> 4, ch = t & 15;
            const int grow = R0 + row;
            if (grow < N_NODES) {
                u32x4 vv = *reinterpret_cast<const u32x4*>(&qt[row][ch * 16]);
                *reinterpret_cast<u32x4*>(UVq + (size_t)grow * 256 + ch * 16) = vv;
            }
        }
        __syncthreads();
        tile = next;
    }
}

// ---------------------------------------------------------------------------
// Edge combine v6 (int8): out[e] = sum_d relu(sU*(uq-128) + sV*(vq-128))*W2 + b2
// 8 lanes/edge x 16 dims/lane, 16B int8 chunks: 18 lane-requests/edge vs 32.
// Same proven v3 schedule: coalesced id load + shfl broadcast, all gathers
// issued before consumes, next ids prefetched under compute.
// ---------------------------------------------------------------------------
__device__ __forceinline__ float dot16q(u32x4 u, u32x4 v, float su, float sv,
                                        const float* w2) {
    const float off = -128.f * (su + sv);
    float a = 0.f;
    #pragma unroll
    for (int q = 0; q < 4; ++q) {
        const unsigned uu = u[q], vv = v[q];
        #pragma unroll
        for (int b = 0; b < 4; ++b) {
            const float cu = (float)((uu >> (8 * b)) & 255u);
            const float cv = (float)((vv >> (8 * b)) & 255u);
            float tt = fmaf(su, cu, fmaf(sv, cv, off));
            tt = tt > 0.f ? tt : 0.f;
            a = fmaf(tt, w2[q * 4 + b], a);
        }
    }
    return a;
}

__global__ __launch_bounds__(256) void edge_combine6_kernel(
    const unsigned char* __restrict__ UVq,
    const float2* __restrict__ scl,
    const int*   __restrict__ src,
    const int*   __restrict__ dst,
    const float* __restrict__ W2,
    const float* __restrict__ b2,
    float* __restrict__ out)
{
    const int t  = threadIdx.x;
    const int w  = t >> 6;
    const int l  = t & 63;
    const int eg = l >> 3;         // edge-in-sub-batch 0..7
    const int dg = l & 7;          // dim group 0..7 (dims dg*16..+15)

    float w2v[16];
    #pragma unroll
    for (int j = 0; j < 16; ++j) w2v[j] = W2[dg * 16 + j];
    const float b2v = b2[0];

    const int gw = blockIdx.x * 4 + w;
    const int stride = gridDim.x * 4 * 32;

    int base = gw * 32;
    int jj0 = base + (l & 31); if (jj0 > N_EDGES - 1) jj0 = N_EDGES - 1;
    int ids = (l < 32) ? src[jj0] : dst[jj0];

    for (; base < N_EDGES; base += stride) {
        // per-edge scales: lane<32 needs sU(src), lane>=32 needs sV(dst)
        const float2 sc2 = scl[ids];
        const float sval = (l < 32) ? sc2.x : sc2.y;

        const int s0 = __shfl(ids, 0 * 8 + eg, 64), d0 = __shfl(ids, 32 + 0 * 8 + eg, 64);
        const int s1 = __shfl(ids, 1 * 8 + eg, 64), d1 = __shfl(ids, 32 + 1 * 8 + eg, 64);
        const int s2 = __shfl(ids, 2 * 8 + eg, 64), d2 = __shfl(ids, 32 + 2 * 8 + eg, 64);
        const int s3 = __shfl(ids, 3 * 8 + eg, 64), d3 = __shfl(ids, 32 + 3 * 8 + eg, 64);

        // issue all 8 gathers (16B int8 each) before any consume
        u32x4 uq0 = *(const u32x4*)(UVq + (size_t)s0 * 256 + dg * 16);
        u32x4 vq0 = *(const u32x4*)(UVq + (size_t)d0 * 256 + 128 + dg * 16);
        u32x4 uq1 = *(const u32x4*)(UVq + (size_t)s1 * 256 + dg * 16);
        u32x4 vq1 = *(const u32x4*)(UVq + (size_t)d1 * 256 + 128 + dg * 16);
        u32x4 uq2 = *(const u32x4*)(UVq + (size_t)s2 * 256 + dg * 16);
        u32x4 vq2 = *(const u32x4*)(UVq + (size_t)d2 * 256 + 128 + dg * 16);
        u32x4 uq3 = *(const u32x4*)(UVq + (size_t)s3 * 256 + dg * 16);
        u32x4 vq3 = *(const u32x4*)(UVq + (size_t)d3 * 256 + 128 + dg * 16);

        // prefetch next iteration's ids under the gather latency
        const int nb = base + stride;
        if (nb < N_EDGES) {
            int j2 = nb + (l & 31); if (j2 > N_EDGES - 1) j2 = N_EDGES - 1;
            ids = (l < 32) ? src[j2] : dst[j2];
        }
        __builtin_amdgcn_sched_barrier(0);

        const float su0 = __shfl(sval, 0 * 8 + eg, 64), sv0 = __shfl(sval, 32 + 0 * 8 + eg, 64);
        const float su1 = __shfl(sval, 1 * 8 + eg, 64), sv1 = __shfl(sval, 32 + 1 * 8 + eg, 64);
        const float su2 = __shfl(sval, 2 * 8 + eg, 64), sv2 = __shfl(sval, 32 + 2 * 8 + eg, 64);
        const float su3 = __shfl(sval, 3 * 8 + eg, 64), sv3 = __shfl(sval, 32 + 3 * 8 + eg, 64);

        float a0 = dot16q(uq0, vq0, su0, sv0, w2v);
        float a1 = dot16q(uq1, vq1, su1, sv1, w2v);
        float a2 = dot16q(uq2, vq2, su2, sv2, w2v);
        float a3 = dot16q(uq3, vq3, su3, sv3, w2v);

        #pragma unroll
        for (int m = 1; m <= 4; m <<= 1) {
            a0 += __shfl_xor(a0, m, 64);
            a1 += __shfl_xor(a1, m, 64);
            a2 += __shfl_xor(a2, m, 64);
            a3 += __shfl_xor(a3, m, 64);
        }

        if (dg == 0) {
            if (base + 0 * 8 + eg < N_EDGES) __builtin_nontemporal_store(a0 + b2v, &out[base + 0 * 8 + eg]);
            if (base + 1 * 8 + eg < N_EDGES) __builtin_nontemporal_store(a1 + b2v, &out[base + 1 * 8 + eg]);
            if (base + 2 * 8 + eg < N_EDGES) __builtin_nontemporal_store(a2 + b2v, &out[base + 2 * 8 + eg]);
            if (base + 3 * 8 + eg < N_EDGES) __builtin_nontemporal_store(a3 + b2v, &out[base + 3 * 8 + eg]);
        }
    }
}

// ---------------------------------------------------------------------------
// v2 fallback (only if ws too small): bf16 h + direct-gather MFMA
// ---------------------------------------------------------------------------
__global__ void conv_h_kernel(const float* __restrict__ h, short* __restrict__ hb) {
    int i = blockIdx.x * blockDim.x + threadIdx.x;
    const int n8 = N_NODES * HF / 8;
    if (i < n8) {
        f32x4 a = ((const f32x4*)h)[i * 2];
        f32x4 b = ((const f32x4*)h)[i * 2 + 1];
        s16x8 p;
        p[0]=f2bf(a[0]); p[1]=f2bf(a[1]); p[2]=f2bf(a[2]); p[3]=f2bf(a[3]);
        p[4]=f2bf(b[0]); p[5]=f2bf(b[1]); p[6]=f2bf(b[2]); p[7]=f2bf(b[3]);
        ((s16x8*)hb)[i] = p;
    }
}

__device__ __forceinline__ void gatherA(const short* __restrict__ hb,
                                        int sid, int did, int lg, s16x8 (&A)[8]) {
    const s16x8* bs = (const s16x8*)(hb + (size_t)sid * HF);
    const s16x8* bd = (const s16x8*)(hb + (size_t)did * HF);
    A[0] = bs[lg];      A[1] = bs[4 + lg];  A[2] = bs[8 + lg];  A[3] = bs[12 + lg];
    A[4] = bd[lg];      A[5] = bd[4 + lg];  A[6] = bd[8 + lg];  A[7] = bd[12 + lg];
}

__device__ __forceinline__ void step_tile_v2(
    int tile, int g,
    const short* __restrict__ hb,
    const int* __restrict__ src, const int* __restrict__ dst,
    s16x8 (&Acur)[8], s16x8 (&Anext)[8],
    int sidg, int didg, int& sid2, int& did2,
    const s16x8 (&bfrag)[8][4],
    const float (&b1v)[4], const float (&w2v)[4], float b2v,
    float* __restrict__ out,
    float (&lds_p)[2][2][MTILE], int pp,
    int t, int r, int c, int lg, int lr, int myrow)
{
    gatherA(hb, sidg, didg, lg, Anext);
    {
        int e = (tile + 2 * g) * MTILE + myrow;
        e = e < N_EDGES ? e : N_EDGES - 1;
        sid2 = src[e]; did2 = dst[e];
    }
    f32x4 acc[4];
    #pragma unroll
    for (int nt = 0; nt < 4; ++nt) acc[nt] = (f32x4){0.f, 0.f, 0.f, 0.f};
    #pragma unroll
    for (int kt = 0; kt < 8; ++kt)
        #pragma unroll
        for (int nt = 0; nt < 4; ++nt)
            acc[nt] = __builtin_amdgcn_mfma_f32_16x16x32_bf16(Acur[kt], bfrag[kt][nt], acc[nt], 0, 0, 0);

    float s0[4];
    #pragma unroll
    for (int rr = 0; rr < 4; ++rr) {
        float a = 0.f;
        #pragma unroll
        for (int nt = 0; nt < 4; ++nt) {
            float v = acc[nt][rr] + b1v[nt];
            v = v > 0.f ? v : 0.f;
            a += v * w2v[nt];
        }
        s0[rr] = a;
    }
    #pragma unroll
    for (int mask = 1; mask <= 8; mask <<= 1)
        #pragma unroll
        for (int rr = 0; rr < 4; ++rr)
            s0[rr] += __shfl_xor(s0[rr], mask, 64);

    if (lr == 0) {
        #pragma unroll
        for (int rr = 0; rr < 4; ++rr)
            lds_p[pp][c][r * 16 + lg * 4 + rr] = s0[rr];
    }
    asm volatile("s_waitcnt lgkmcnt(0)" ::: "memory");
    __builtin_amdgcn_s_barrier();
    asm volatile("" ::: "memory");

    if (t < MTILE) {
        int e = tile * MTILE + t;
        if (e < N_EDGES)
            out[e] = lds_p[pp][0][t] + lds_p[pp][1][t] + b2v;
    }
}

__global__ __launch_bounds__(512, 2) void mlp_edge_score_v2(
    const short* __restrict__ hb,
    const int*   __restrict__ src,
    const int*   __restrict__ dst,
    const float* __restrict__ W1,
    const float* __restrict__ b1,
    const float* __restrict__ W2,
    const float* __restrict__ b2,
    float* __restrict__ out)
{
    __shared__ float lds_p[2][2][MTILE];

    const int t  = threadIdx.x;
    const int w  = t >> 6;
    const int l  = t & 63;
    const int r  = w >> 1;
    const int c  = w & 1;
    const int lg = l >> 4;
    const int lr = l & 15;
    const int myrow = r * 16 + lr;

    s16x8 bfrag[8][4];
    #pragma unroll
    for (int kt = 0; kt < 8; ++kt)
        #pragma unroll
        for (int nt = 0; nt < 4; ++nt) {
            const int n  = c * 64 + nt * 16 + lr;
            const int kb = kt * 32 + lg * 8;
            s16x8 f;
            #pragma unroll
            for (int i = 0; i < 8; ++i) f[i] = f2bf(W1[(size_t)(kb + i) * HF + n]);
            bfrag[kt][nt] = f;
        }
    float b1v[4], w2v[4];
    #pragma unroll
    for (int nt = 0; nt < 4; ++nt) {
        const int n = c * 64 + nt * 16 + lr;
        b1v[nt] = b1[n];
        w2v[nt] = W2[n];
    }
    const float b2v = b2[0];

    const int g = gridDim.x;
    const int tile0 = blockIdx.x;

    s16x8 Aa[8], Ab[8];
    {
        int e = tile0 * MTILE + myrow;
        e = e < N_EDGES ? e : N_EDGES - 1;
        gatherA(hb, src[e], dst[e], lg, Aa);
    }
    int sidA, didA, sidB, didB;
    {
        int e = (tile0 + g) * MTILE + myrow;
        e = e < N_EDGES ? e : N_EDGES - 1;
        sidA = src[e]; didA = dst[e];
    }

    int pp = 0;
    for (int tile = tile0; tile < NTILES; tile += 2 * g) {
        step_tile_v2(tile, g, hb, src, dst, Aa, Ab, sidA, didA, sidB, didB,
                     bfrag, b1v, w2v, b2v, out, lds_p, pp, t, r, c, lg, lr, myrow);
        pp ^= 1;
        if (tile + g < NTILES) {
            step_tile_v2(tile + g, g, hb, src, dst, Ab, Aa, sidB, didB, sidA, didA,
                         bfrag, b1v, w2v, b2v, out, lds_p, pp, t, r, c, lg, lr, myrow);
            pp ^= 1;
        }
    }
}

extern "C" void kernel_launch(void* const* d_in, const int* in_sizes, int n_in,
                              void* d_out, int out_size, void* d_ws, size_t ws_size,
                              hipStream_t stream) {
    const float* h   = (const float*)d_in[0];
    const int*   src = (const int*)  d_in[1];
    const int*   dst = (const int*)  d_in[2];
    const float* W1  = (const float*)d_in[3];
    const float* b1  = (const float*)d_in[4];
    const float* W2  = (const float*)d_in[5];
    const float* b2  = (const float*)d_in[6];
    float* out = (float*)d_out;

    if (ws_size >= WS_NEED) {
        char* ws = (char*)d_ws;
        short* w1f = (short*)ws;
        unsigned char* UVq = (unsigned char*)(ws + W1F_BYTES);
        float2* scl = (float2*)(ws + W1F_BYTES + UVQ_BYTES);

        conv_w_kernel<<<16, 256, 0, stream>>>(W1, w1f);
        uv_gemm7_kernel<<<1024, 256, 0, stream>>>(h, w1f, b1, UVq, scl);
        edge_combine6_kernel<<<1024, 256, 0, stream>>>(UVq, scl, src, dst, W2, b2, out);
    } else {
        short* hb = (short*)d_ws;
        const int n8 = N_NODES * HF / 8;
        conv_h_kernel<<<(n8 + 255) / 256, 256, 0, stream>>>(h, hb);
        mlp_edge_score_v2<<<256, 512, 0, stream>>>(hb, src, dst, W1, b1, W2, b2, out);
    }
}